// Round 6
// baseline (1942.145 us; speedup 1.0000x reference)
//
#include <hip/hip_runtime.h>
#include <math.h>

#define FD 128
#define NOUT 16
#define ALPHA_F 0.1f

typedef short short8 __attribute__((ext_vector_type(8)));
typedef float f32x4 __attribute__((ext_vector_type(4)));

// ---------- bf16 helpers (bit-level, RNE) ----------
__device__ __forceinline__ float bflo(unsigned u) { return __uint_as_float(u << 16); }
__device__ __forceinline__ float bfhi(unsigned u) { return __uint_as_float(u & 0xffff0000u); }
__device__ __forceinline__ unsigned f2bf(float f) {
    unsigned u = __float_as_uint(f);
    u += 0x7fffu + ((u >> 16) & 1u);          // round-to-nearest-even
    return u >> 16;
}
__device__ __forceinline__ unsigned pack2(float a, float b) {
    return f2bf(a) | (f2bf(b) << 16);
}

// ---------- CSC build ----------

__global__ void count_kernel(const int* __restrict__ cols, int* __restrict__ cnt, int e) {
    int i = blockIdx.x * blockDim.x + threadIdx.x;
    if (i < e) atomicAdd(&cnt[cols[i]], 1);
}

__global__ void dinv_kernel(const int* __restrict__ cnt, float* __restrict__ dinv, int n) {
    int i = blockIdx.x * blockDim.x + threadIdx.x;
    if (i < n) dinv[i] = rsqrtf((float)(cnt[i] + 1));   // +1 self-loop
}

// padded degree: true degree (cnt+1) rounded up to multiple of 8
__device__ __forceinline__ int padded(int cnt) { return (cnt + 8) & ~7; }

// three-kernel exclusive scan of padded degrees
__global__ void scan_partial_kernel(const int* __restrict__ cnt, int* __restrict__ bsum, int n) {
    __shared__ int sh[256];
    int base = blockIdx.x * 1024 + threadIdx.x * 4;
    int s = 0;
    #pragma unroll
    for (int j = 0; j < 4; ++j) { int i = base + j; if (i < n) s += padded(cnt[i]); }
    sh[threadIdx.x] = s; __syncthreads();
    for (int d = 128; d > 0; d >>= 1) {
        if ((int)threadIdx.x < d) sh[threadIdx.x] += sh[threadIdx.x + d];
        __syncthreads();
    }
    if (threadIdx.x == 0) bsum[blockIdx.x] = sh[0];
}

__global__ void scan_base_kernel(int* __restrict__ bsum, int* __restrict__ off, int nb, int n) {
    if (threadIdx.x == 0 && blockIdx.x == 0) {
        int run = 0;
        for (int b = 0; b < nb; ++b) { int t = bsum[b]; bsum[b] = run; run += t; }
        off[n] = run;
    }
}

// writes off[i] and cur[i]=off[i]. cnt and cur alias (read-before-write per thread).
__global__ void scan_final_kernel(const int* __restrict__ cnt, const int* __restrict__ bsum,
                                  int* __restrict__ off, int* __restrict__ cur, int n) {
    __shared__ int sh[256];
    int t = threadIdx.x;
    int base_i = blockIdx.x * 1024 + t * 4;
    int v[4]; int s = 0;
    #pragma unroll
    for (int j = 0; j < 4; ++j) { int i = base_i + j; v[j] = (i < n) ? padded(cnt[i]) : 0; s += v[j]; }
    sh[t] = s; __syncthreads();
    for (int d = 1; d < 256; d <<= 1) {
        int x = (t >= d) ? sh[t - d] : 0;
        __syncthreads();
        sh[t] += x;
        __syncthreads();
    }
    int excl = sh[t] - s + bsum[blockIdx.x];
    #pragma unroll
    for (int j = 0; j < 4; ++j) {
        int i = base_i + j;
        if (i < n) { off[i] = excl; cur[i] = excl; }
        excl += v[j];
    }
}

// edge record: low16 = src node id, high16 = bf16 weight
__global__ void fill_edges_kernel(const int* __restrict__ rows, const int* __restrict__ cols,
                                  const float* __restrict__ dinv, int* __restrict__ cur,
                                  unsigned* __restrict__ eg, int e) {
    int i = blockIdx.x * blockDim.x + threadIdx.x;
    if (i < e) {
        int r = rows[i];
        int c = cols[i];
        int pos = atomicAdd(&cur[c], 1);
        eg[pos] = (f2bf(dinv[r] * dinv[c]) << 16) | (unsigned)r;
    }
}

__global__ void fill_loops_kernel(const float* __restrict__ dinv, int* __restrict__ cur,
                                  unsigned* __restrict__ eg, int n) {
    int i = blockIdx.x * blockDim.x + threadIdx.x;
    if (i < n) {
        int pos = atomicAdd(&cur[i], 1);
        eg[pos] = (f2bf(dinv[i] * dinv[i]) << 16) | (unsigned)i;
    }
}

// ---------- pre-processing for MFMA GEMM ----------

// Wt[c][ku] = pack2(W[2ku][c], W[2ku+1][c]) : transposed, bf16-packed. 128x64 uints.
__global__ void wtrans_kernel(const float* __restrict__ W, unsigned* __restrict__ Wt) {
    int idx = blockIdx.x * 256 + threadIdx.x;
    if (idx < 128 * 64) {
        int c = idx >> 6, ku = idx & 63;
        Wt[idx] = pack2(W[(2 * ku) * FD + c], W[(2 * ku + 1) * FD + c]);
    }
}

// convert fp32 features -> packed bf16 (2 per uint)
__global__ void xconv_kernel(const float* __restrict__ x, unsigned* __restrict__ Xb, int total) {
    int idx = blockIdx.x * blockDim.x + threadIdx.x;
    if (idx < total) {
        float2 f = ((const float2*)x)[idx];
        Xb[idx] = pack2(f.x, f.y);
    }
}

// ---------- MFMA GEMM:  Y = X@W + b ; Ab = bf16(Y), Z0b = bf16(alpha*Y) ----------
// 256 thr = 4 waves; block covers 64 rows; wave w -> rows [blk*64+w*16, +16).
// K=128 in 4 steps of 32; N=128 as 8 tiles of 16. B^T (Wt) convention per m89/m92.
__global__ __launch_bounds__(256, 4)
void gemm_mfma_kernel(const unsigned* __restrict__ Xb, const unsigned* __restrict__ Wt,
                      const float* __restrict__ bias,
                      unsigned* __restrict__ Ab, unsigned* __restrict__ Z0b, int n) {
    int l = threadIdx.x & 63;
    int w = threadIdx.x >> 6;
    int l15 = l & 15, lq = l >> 4;
    int r0 = blockIdx.x * 64 + w * 16;
    int arow = min(r0 + l15, n - 1);
    const unsigned* aptr = Xb + (size_t)arow * 64 + lq * 4;
    const unsigned* bptr = Wt + (size_t)l15 * 64 + lq * 4;

    f32x4 acc[8];
    #pragma unroll
    for (int nt = 0; nt < 8; ++nt) acc[nt] = (f32x4){0.f, 0.f, 0.f, 0.f};

    #pragma unroll
    for (int kk = 0; kk < 4; ++kk) {
        short8 af = *(const short8*)(aptr + kk * 16);
        #pragma unroll
        for (int nt = 0; nt < 8; ++nt) {
            short8 bf = *(const short8*)(bptr + nt * 1024 + kk * 16);
            acc[nt] = __builtin_amdgcn_mfma_f32_16x16x32_bf16(af, bf, acc[nt], 0, 0, 0);
        }
    }

    #pragma unroll
    for (int nt = 0; nt < 8; ++nt) {
        float b_ = bias[nt * 16 + l15];
        #pragma unroll
        for (int j = 0; j < 4; ++j) {
            float v = acc[nt][j] + b_;
            float vp = __shfl_xor(v, 1);
            int row = r0 + lq * 4 + j;
            if (!(l & 1) && row < n) {
                int cu = nt * 8 + (l15 >> 1);
                Ab[(size_t)row * 64 + cu]  = pack2(v, vp);
                Z0b[(size_t)row * 64 + cu] = pack2(ALPHA_F * v, ALPHA_F * vp);
            }
        }
    }
}

// ---------- APPNP step, feature-sliced for per-XCD L2 residency ----------
// 4 slices of 32 features (64 B, line-aligned). slice = blockIdx.x % 4, so with
// the b%8 -> XCD round-robin each XCD serves ONE slice: gather working set
// 50000*64B = 3.2 MB < 4 MB L2. One wave per node-slice; 4 edge-subgroups of
// 16 lanes; cross-group reduce via 2 shuffles. Degrees padded to mult of 8
// (zero-weight recs) -> uniform branch-free loop.
__global__ __launch_bounds__(256, 8)
void spmm_sliced_kernel(const int* __restrict__ off, const unsigned* __restrict__ eg,
                        const unsigned* __restrict__ Xin, const unsigned* __restrict__ X0b,
                        unsigned* __restrict__ Xout, int n, int relu) {
    int b = blockIdx.x;
    int s = b & 3;                                        // feature slice
    int node = ((b >> 2) << 2) + ((int)threadIdx.x >> 6); // 4 nodes per block
    if (node >= n) return;
    int l = threadIdx.x & 63;
    int esub = l >> 4;           // edge subgroup 0..3
    int fu = l & 15;             // uint (2 features) within slice
    int p0 = off[node];
    int deg = off[node + 1] - p0;                         // multiple of 8
    const unsigned* Xs = Xin + s * 16 + fu;
    unsigned x0 = X0b[(size_t)node * 64 + s * 16 + fu];   // issue early
    const unsigned* ep = eg + p0 + esub;

    float a0 = 0.f, a1 = 0.f;
    int c = 0;
    for (; c + 16 <= deg; c += 16) {                      // 16 edges, 4 gathers in flight
        unsigned r0 = ep[c + 0];
        unsigned r1 = ep[c + 4];
        unsigned r2 = ep[c + 8];
        unsigned r3 = ep[c + 12];
        unsigned g0 = Xs[(r0 & 0xffffu) * 64u];
        unsigned g1 = Xs[(r1 & 0xffffu) * 64u];
        unsigned g2 = Xs[(r2 & 0xffffu) * 64u];
        unsigned g3 = Xs[(r3 & 0xffffu) * 64u];
        float w0 = bfhi(r0), w1 = bfhi(r1), w2 = bfhi(r2), w3 = bfhi(r3);
        a0 += w0 * bflo(g0); a1 += w0 * bfhi(g0);
        a0 += w1 * bflo(g1); a1 += w1 * bfhi(g1);
        a0 += w2 * bflo(g2); a1 += w2 * bfhi(g2);
        a0 += w3 * bflo(g3); a1 += w3 * bfhi(g3);
    }
    if (c < deg) {                                        // one 8-edge tail
        unsigned r0 = ep[c + 0];
        unsigned r1 = ep[c + 4];
        unsigned g0 = Xs[(r0 & 0xffffu) * 64u];
        unsigned g1 = Xs[(r1 & 0xffffu) * 64u];
        float w0 = bfhi(r0), w1 = bfhi(r1);
        a0 += w0 * bflo(g0); a1 += w0 * bfhi(g0);
        a0 += w1 * bflo(g1); a1 += w1 * bfhi(g1);
    }

    // reduce across the 4 edge-subgroups (lanes ^16, ^32)
    a0 += __shfl_xor(a0, 16); a0 += __shfl_xor(a0, 32);
    a1 += __shfl_xor(a1, 16); a1 += __shfl_xor(a1, 32);

    if (esub == 0) {
        float v0 = 0.9f * a0 + bflo(x0);
        float v1 = 0.9f * a1 + bfhi(x0);
        if (relu) { v0 = fmaxf(v0, 0.f); v1 = fmaxf(v1, 0.f); }
        Xout[(size_t)node * 64 + s * 16 + fu] = pack2(v0, v1);
    }
}

// ---------- head: logits = H @ Wc + bc ; log_softmax. 16 lanes/node ----------
__global__ void head_kernel(const unsigned* __restrict__ Hb, const float* __restrict__ Wc,
                            const float* __restrict__ bc, float* __restrict__ out, int n) {
    int t = threadIdx.x;
    int o = t & (NOUT - 1);
    int node = blockIdx.x * (256 / NOUT) + (t >> 4);
    if (node >= n) return;
    float acc = bc[o];
    const uint4* hrow = (const uint4*)(Hb + (size_t)node * 64);
    #pragma unroll 4
    for (int k4 = 0; k4 < 16; ++k4) {
        uint4 u = hrow[k4];
        int k = k4 * 8;
        acc += bflo(u.x) * Wc[(k + 0) * NOUT + o];
        acc += bfhi(u.x) * Wc[(k + 1) * NOUT + o];
        acc += bflo(u.y) * Wc[(k + 2) * NOUT + o];
        acc += bfhi(u.y) * Wc[(k + 3) * NOUT + o];
        acc += bflo(u.z) * Wc[(k + 4) * NOUT + o];
        acc += bfhi(u.z) * Wc[(k + 5) * NOUT + o];
        acc += bflo(u.w) * Wc[(k + 6) * NOUT + o];
        acc += bfhi(u.w) * Wc[(k + 7) * NOUT + o];
    }
    float m = acc;
    #pragma unroll
    for (int d = NOUT / 2; d > 0; d >>= 1) m = fmaxf(m, __shfl_xor(m, d, NOUT));
    float ex = __expf(acc - m);
    float s = ex;
    #pragma unroll
    for (int d = NOUT / 2; d > 0; d >>= 1) s += __shfl_xor(s, d, NOUT);
    out[node * NOUT + o] = acc - m - __logf(s);
}

// ---------- launch ----------

static inline size_t align256(size_t x) { return (x + 255) & ~(size_t)255; }

extern "C" void kernel_launch(void* const* d_in, const int* in_sizes, int n_in,
                              void* d_out, int out_size, void* d_ws, size_t ws_size,
                              hipStream_t stream) {
    const float* x  = (const float*)d_in[0];
    const int*   ei = (const int*)d_in[1];
    const float* W1 = (const float*)d_in[2];
    const float* b1 = (const float*)d_in[3];
    const float* W2 = (const float*)d_in[4];
    const float* b2 = (const float*)d_in[5];
    const float* W3 = (const float*)d_in[6];
    const float* b3 = (const float*)d_in[7];
    const float* Wc = (const float*)d_in[8];
    const float* bc = (const float*)d_in[9];
    float* out = (float*)d_out;

    const int n = in_sizes[0] / FD;       // 50000
    const int e = in_sizes[1] / 2;        // 800000
    const int nnz_max = e + n + 8 * n + 16;   // padded upper bound
    const int nb = (n + 1023) / 1024;

    const int* rows = ei;
    const int* cols = ei + e;

    // workspace layout (~57 MB)
    char* p = (char*)d_ws;
    int*      off  = (int*)p;       p += align256((size_t)(n + 1) * 4);
    int*      cur  = (int*)p;       p += align256((size_t)n * 4);
    float*    dinv = (float*)p;     p += align256((size_t)n * 4);
    int*      bsum = (int*)p;       p += align256((size_t)nb * 4);
    unsigned* eg   = (unsigned*)p;  p += align256((size_t)nnz_max * 4);
    unsigned* Wt   = (unsigned*)p;  p += align256((size_t)3 * 8192 * 4);
    unsigned* Ab   = (unsigned*)p;  p += align256((size_t)n * 64 * 4);
    unsigned* Bb   = (unsigned*)p;  p += align256((size_t)n * 64 * 4);
    unsigned* Z0b  = (unsigned*)p;  p += align256((size_t)n * 64 * 4);
    unsigned* Hb   = (unsigned*)p;  p += align256((size_t)n * 64 * 4);

    // ---- build padded CSC ----
    hipMemsetAsync(cur, 0, (size_t)n * 4, stream);
    hipMemsetAsync(eg, 0, (size_t)nnz_max * 4, stream);
    count_kernel<<<(e + 255) / 256, 256, 0, stream>>>(cols, cur, e);
    dinv_kernel<<<(n + 255) / 256, 256, 0, stream>>>(cur, dinv, n);
    scan_partial_kernel<<<nb, 256, 0, stream>>>(cur, bsum, n);
    scan_base_kernel<<<1, 64, 0, stream>>>(bsum, off, nb, n);
    scan_final_kernel<<<nb, 256, 0, stream>>>(cur, bsum, off, cur, n);
    fill_edges_kernel<<<(e + 255) / 256, 256, 0, stream>>>(rows, cols, dinv, cur, eg, e);
    fill_loops_kernel<<<(n + 255) / 256, 256, 0, stream>>>(dinv, cur, eg, n);

    // ---- weight transpose + input convert ----
    wtrans_kernel<<<32, 256, 0, stream>>>(W1, Wt);
    wtrans_kernel<<<32, 256, 0, stream>>>(W2, Wt + 8192);
    wtrans_kernel<<<32, 256, 0, stream>>>(W3, Wt + 16384);
    xconv_kernel<<<(n * 64 + 255) / 256, 256, 0, stream>>>(x, Hb, n * 64);

    const int gemm_grid = (n + 63) / 64;
    const int spmm_grid = ((n + 3) / 4) * 4;   // 4 slices x node-chunks
    const float* bl[3] = { b1, b2, b3 };

    for (int st = 0; st < 3; ++st) {
        gemm_mfma_kernel<<<gemm_grid, 256, 0, stream>>>(Hb, Wt + st * 8192, bl[st], Ab, Z0b, n);
        unsigned* bufs[2] = { Ab, Bb };
        int cu = 0;
        for (int k = 0; k < 10; ++k) {
            unsigned* o_ = (k == 9) ? Hb : bufs[cu ^ 1];
            spmm_sliced_kernel<<<spmm_grid, 256, 0, stream>>>(off, eg, bufs[cu], Z0b, o_, n, k == 9);
            cu ^= 1;
        }
    }

    head_kernel<<<(n + 15) / 16, 256, 0, stream>>>(Hb, Wc, bc, out, n);
}

// Round 7
// 1212.622 us; speedup vs baseline: 1.6016x; 1.6016x over previous
//
#include <hip/hip_runtime.h>
#include <math.h>

#define FD 128
#define NOUT 16
#define ALPHA_F 0.1f

typedef short short8 __attribute__((ext_vector_type(8)));
typedef float f32x4 __attribute__((ext_vector_type(4)));

// ---------- bf16 helpers (bit-level, RNE) ----------
__device__ __forceinline__ float bflo(unsigned u) { return __uint_as_float(u << 16); }
__device__ __forceinline__ float bfhi(unsigned u) { return __uint_as_float(u & 0xffff0000u); }
__device__ __forceinline__ unsigned f2bf(float f) {
    unsigned u = __float_as_uint(f);
    u += 0x7fffu + ((u >> 16) & 1u);          // round-to-nearest-even
    return u >> 16;
}
__device__ __forceinline__ unsigned pack2(float a, float b) {
    return f2bf(a) | (f2bf(b) << 16);
}

// ---------- CSC build ----------

__global__ void count_kernel(const int* __restrict__ cols, int* __restrict__ cnt, int e) {
    int i = blockIdx.x * blockDim.x + threadIdx.x;
    if (i < e) atomicAdd(&cnt[cols[i]], 1);
}

__global__ void dinv_kernel(const int* __restrict__ cnt, float* __restrict__ dinv, int n) {
    int i = blockIdx.x * blockDim.x + threadIdx.x;
    if (i < n) dinv[i] = rsqrtf((float)(cnt[i] + 1));   // +1 self-loop
}

// padded degree: true degree (cnt+1) rounded up to multiple of 8
__device__ __forceinline__ int padded(int cnt) { return (cnt + 8) & ~7; }

// three-kernel exclusive scan of padded degrees
__global__ void scan_partial_kernel(const int* __restrict__ cnt, int* __restrict__ bsum, int n) {
    __shared__ int sh[256];
    int base = blockIdx.x * 1024 + threadIdx.x * 4;
    int s = 0;
    #pragma unroll
    for (int j = 0; j < 4; ++j) { int i = base + j; if (i < n) s += padded(cnt[i]); }
    sh[threadIdx.x] = s; __syncthreads();
    for (int d = 128; d > 0; d >>= 1) {
        if ((int)threadIdx.x < d) sh[threadIdx.x] += sh[threadIdx.x + d];
        __syncthreads();
    }
    if (threadIdx.x == 0) bsum[blockIdx.x] = sh[0];
}

__global__ void scan_base_kernel(int* __restrict__ bsum, int* __restrict__ off, int nb, int n) {
    if (threadIdx.x == 0 && blockIdx.x == 0) {
        int run = 0;
        for (int b = 0; b < nb; ++b) { int t = bsum[b]; bsum[b] = run; run += t; }
        off[n] = run;
    }
}

// writes off[i] and cur[i]=off[i]. cnt and cur alias (read-before-write per thread).
__global__ void scan_final_kernel(const int* __restrict__ cnt, const int* __restrict__ bsum,
                                  int* __restrict__ off, int* __restrict__ cur, int n) {
    __shared__ int sh[256];
    int t = threadIdx.x;
    int base_i = blockIdx.x * 1024 + t * 4;
    int v[4]; int s = 0;
    #pragma unroll
    for (int j = 0; j < 4; ++j) { int i = base_i + j; v[j] = (i < n) ? padded(cnt[i]) : 0; s += v[j]; }
    sh[t] = s; __syncthreads();
    for (int d = 1; d < 256; d <<= 1) {
        int x = (t >= d) ? sh[t - d] : 0;
        __syncthreads();
        sh[t] += x;
        __syncthreads();
    }
    int excl = sh[t] - s + bsum[blockIdx.x];
    #pragma unroll
    for (int j = 0; j < 4; ++j) {
        int i = base_i + j;
        if (i < n) { off[i] = excl; cur[i] = excl; }
        excl += v[j];
    }
}

// edge record: low16 = src node id, high16 = bf16 weight
__global__ void fill_edges_kernel(const int* __restrict__ rows, const int* __restrict__ cols,
                                  const float* __restrict__ dinv, int* __restrict__ cur,
                                  unsigned* __restrict__ eg, int e) {
    int i = blockIdx.x * blockDim.x + threadIdx.x;
    if (i < e) {
        int r = rows[i];
        int c = cols[i];
        int pos = atomicAdd(&cur[c], 1);
        eg[pos] = (f2bf(dinv[r] * dinv[c]) << 16) | (unsigned)r;
    }
}

__global__ void fill_loops_kernel(const float* __restrict__ dinv, int* __restrict__ cur,
                                  unsigned* __restrict__ eg, int n) {
    int i = blockIdx.x * blockDim.x + threadIdx.x;
    if (i < n) {
        int pos = atomicAdd(&cur[i], 1);
        eg[pos] = (f2bf(dinv[i] * dinv[i]) << 16) | (unsigned)i;
    }
}

// ---------- pre-processing for MFMA GEMM ----------

// Wt[c][ku] = pack2(W[2ku][c], W[2ku+1][c]) : transposed, bf16-packed. 128x64 uints.
__global__ void wtrans_kernel(const float* __restrict__ W, unsigned* __restrict__ Wt) {
    int idx = blockIdx.x * 256 + threadIdx.x;
    if (idx < 128 * 64) {
        int c = idx >> 6, ku = idx & 63;
        Wt[idx] = pack2(W[(2 * ku) * FD + c], W[(2 * ku + 1) * FD + c]);
    }
}

// convert fp32 features -> packed bf16 (2 per uint)
__global__ void xconv_kernel(const float* __restrict__ x, unsigned* __restrict__ Xb, int total) {
    int idx = blockIdx.x * blockDim.x + threadIdx.x;
    if (idx < total) {
        float2 f = ((const float2*)x)[idx];
        Xb[idx] = pack2(f.x, f.y);
    }
}

// ---------- MFMA GEMM:  Y = X@W + b ; Ab = bf16(Y), Z0b = bf16(alpha*Y) ----------
__global__ __launch_bounds__(256, 4)
void gemm_mfma_kernel(const unsigned* __restrict__ Xb, const unsigned* __restrict__ Wt,
                      const float* __restrict__ bias,
                      unsigned* __restrict__ Ab, unsigned* __restrict__ Z0b, int n) {
    int l = threadIdx.x & 63;
    int w = threadIdx.x >> 6;
    int l15 = l & 15, lq = l >> 4;
    int r0 = blockIdx.x * 64 + w * 16;
    int arow = min(r0 + l15, n - 1);
    const unsigned* aptr = Xb + (size_t)arow * 64 + lq * 4;
    const unsigned* bptr = Wt + (size_t)l15 * 64 + lq * 4;

    f32x4 acc[8];
    #pragma unroll
    for (int nt = 0; nt < 8; ++nt) acc[nt] = (f32x4){0.f, 0.f, 0.f, 0.f};

    #pragma unroll
    for (int kk = 0; kk < 4; ++kk) {
        short8 af = *(const short8*)(aptr + kk * 16);
        #pragma unroll
        for (int nt = 0; nt < 8; ++nt) {
            short8 bf = *(const short8*)(bptr + nt * 1024 + kk * 16);
            acc[nt] = __builtin_amdgcn_mfma_f32_16x16x32_bf16(af, bf, acc[nt], 0, 0, 0);
        }
    }

    #pragma unroll
    for (int nt = 0; nt < 8; ++nt) {
        float b_ = bias[nt * 16 + l15];
        #pragma unroll
        for (int j = 0; j < 4; ++j) {
            float v = acc[nt][j] + b_;
            float vp = __shfl_xor(v, 1);
            int row = r0 + lq * 4 + j;
            if (!(l & 1) && row < n) {
                int cu = nt * 8 + (l15 >> 1);
                Ab[(size_t)row * 64 + cu]  = pack2(v, vp);
                Z0b[(size_t)row * 64 + cu] = pack2(ALPHA_F * v, ALPHA_F * vp);
            }
        }
    }
}

// ---------- APPNP step: Xout = 0.9*A_hat@Xin + Z0b, fp32 accum ----------
// 2 nodes per wave (32 lanes each, uint2 = 4 bf16 features per lane).
// Software-pipelined: chunk k+1's records+gathers are issued before chunk k
// is consumed -> ~20 VMEM in flight per wave (latency-bound hypothesis test).
#define DECLC(S) uint4 ra##S, rb##S; uint2 g0##S, g1##S, g2##S, g3##S, g4##S, g5##S, g6##S, g7##S; float lv##S;

#define LOADC(S, base_) { \
    int p_ = s + min((base_), degpad - 8); \
    lv##S = ((base_) < degpad) ? 1.f : 0.f; \
    ra##S = *(const uint4*)(eg + p_); \
    rb##S = *(const uint4*)(eg + p_ + 4); \
    g0##S = Xg[(ra##S.x & 0xffffu) * 32u + lane31]; \
    g1##S = Xg[(ra##S.y & 0xffffu) * 32u + lane31]; \
    g2##S = Xg[(ra##S.z & 0xffffu) * 32u + lane31]; \
    g3##S = Xg[(ra##S.w & 0xffffu) * 32u + lane31]; \
    g4##S = Xg[(rb##S.x & 0xffffu) * 32u + lane31]; \
    g5##S = Xg[(rb##S.y & 0xffffu) * 32u + lane31]; \
    g6##S = Xg[(rb##S.z & 0xffffu) * 32u + lane31]; \
    g7##S = Xg[(rb##S.w & 0xffffu) * 32u + lane31]; }

#define SLOT(S, R, GG) { \
    float w_ = bfhi(R) * lv##S; \
    a0 += w_ * bflo(GG.x); a1 += w_ * bfhi(GG.x); \
    a2 += w_ * bflo(GG.y); a3 += w_ * bfhi(GG.y); }

#define CONSUME(S) { \
    SLOT(S, ra##S.x, g0##S) SLOT(S, ra##S.y, g1##S) \
    SLOT(S, ra##S.z, g2##S) SLOT(S, ra##S.w, g3##S) \
    SLOT(S, rb##S.x, g4##S) SLOT(S, rb##S.y, g5##S) \
    SLOT(S, rb##S.z, g6##S) SLOT(S, rb##S.w, g7##S) }

#define ROTATE() { \
    raA = raB; rbA = rbB; lvA = lvB; \
    g0A = g0B; g1A = g1B; g2A = g2B; g3A = g3B; \
    g4A = g4B; g5A = g5B; g6A = g6B; g7A = g7B; }

__global__ __launch_bounds__(256, 8)
void spmm_bf16_kernel(const int* __restrict__ off, const unsigned* __restrict__ eg,
                      const unsigned* __restrict__ Xin, const unsigned* __restrict__ X0b,
                      unsigned* __restrict__ Xout, int n, int relu) {
    int node = blockIdx.x * 8 + ((int)threadIdx.x >> 5);
    if (node >= n) return;
    int lane31 = threadIdx.x & 31;
    int s = off[node];
    int degpad = off[node + 1] - s;               // multiple of 8, >= 8
    int dother = __shfl_xor(degpad, 32);          // other half's degpad
    int dm = max(degpad, dother);
    const uint2* Xg = (const uint2*)Xin;
    uint2 x0 = ((const uint2*)X0b)[node * 32 + lane31];   // issue early
    float a0 = 0.f, a1 = 0.f, a2 = 0.f, a3 = 0.f;

    DECLC(A) DECLC(B)
    LOADC(A, 0)
    for (int base = 8; base < dm; base += 8) {
        LOADC(B, base)           // prefetch next chunk while A's loads drain
        CONSUME(A)
        ROTATE()
    }
    CONSUME(A)

    float v0 = 0.9f * a0 + bflo(x0.x);
    float v1 = 0.9f * a1 + bfhi(x0.x);
    float v2 = 0.9f * a2 + bflo(x0.y);
    float v3 = 0.9f * a3 + bfhi(x0.y);
    if (relu) {
        v0 = fmaxf(v0, 0.f); v1 = fmaxf(v1, 0.f);
        v2 = fmaxf(v2, 0.f); v3 = fmaxf(v3, 0.f);
    }
    ((uint2*)Xout)[node * 32 + lane31] = make_uint2(pack2(v0, v1), pack2(v2, v3));
}

// ---------- head: logits = H @ Wc + bc ; log_softmax. 16 lanes/node ----------
__global__ void head_kernel(const unsigned* __restrict__ Hb, const float* __restrict__ Wc,
                            const float* __restrict__ bc, float* __restrict__ out, int n) {
    int t = threadIdx.x;
    int o = t & (NOUT - 1);
    int node = blockIdx.x * (256 / NOUT) + (t >> 4);
    if (node >= n) return;
    float acc = bc[o];
    const uint4* hrow = (const uint4*)(Hb + (size_t)node * 64);
    #pragma unroll 4
    for (int k4 = 0; k4 < 16; ++k4) {
        uint4 u = hrow[k4];
        int k = k4 * 8;
        acc += bflo(u.x) * Wc[(k + 0) * NOUT + o];
        acc += bfhi(u.x) * Wc[(k + 1) * NOUT + o];
        acc += bflo(u.y) * Wc[(k + 2) * NOUT + o];
        acc += bfhi(u.y) * Wc[(k + 3) * NOUT + o];
        acc += bflo(u.z) * Wc[(k + 4) * NOUT + o];
        acc += bfhi(u.z) * Wc[(k + 5) * NOUT + o];
        acc += bflo(u.w) * Wc[(k + 6) * NOUT + o];
        acc += bfhi(u.w) * Wc[(k + 7) * NOUT + o];
    }
    float m = acc;
    #pragma unroll
    for (int d = NOUT / 2; d > 0; d >>= 1) m = fmaxf(m, __shfl_xor(m, d, NOUT));
    float ex = __expf(acc - m);
    float s = ex;
    #pragma unroll
    for (int d = NOUT / 2; d > 0; d >>= 1) s += __shfl_xor(s, d, NOUT);
    out[node * NOUT + o] = acc - m - __logf(s);
}

// ---------- launch ----------

static inline size_t align256(size_t x) { return (x + 255) & ~(size_t)255; }

extern "C" void kernel_launch(void* const* d_in, const int* in_sizes, int n_in,
                              void* d_out, int out_size, void* d_ws, size_t ws_size,
                              hipStream_t stream) {
    const float* x  = (const float*)d_in[0];
    const int*   ei = (const int*)d_in[1];
    const float* W1 = (const float*)d_in[2];
    const float* b1 = (const float*)d_in[3];
    const float* W2 = (const float*)d_in[4];
    const float* b2 = (const float*)d_in[5];
    const float* W3 = (const float*)d_in[6];
    const float* b3 = (const float*)d_in[7];
    const float* Wc = (const float*)d_in[8];
    const float* bc = (const float*)d_in[9];
    float* out = (float*)d_out;

    const int n = in_sizes[0] / FD;       // 50000
    const int e = in_sizes[1] / 2;        // 800000
    const int nnz_max = e + n + 8 * n + 16;   // padded upper bound
    const int nb = (n + 1023) / 1024;

    const int* rows = ei;
    const int* cols = ei + e;

    // workspace layout (~57 MB)
    char* p = (char*)d_ws;
    int*      off  = (int*)p;       p += align256((size_t)(n + 1) * 4);
    int*      cur  = (int*)p;       p += align256((size_t)n * 4);
    float*    dinv = (float*)p;     p += align256((size_t)n * 4);
    int*      bsum = (int*)p;       p += align256((size_t)nb * 4);
    unsigned* eg   = (unsigned*)p;  p += align256((size_t)nnz_max * 4);
    unsigned* Wt   = (unsigned*)p;  p += align256((size_t)3 * 8192 * 4);
    unsigned* Ab   = (unsigned*)p;  p += align256((size_t)n * 64 * 4);
    unsigned* Bb   = (unsigned*)p;  p += align256((size_t)n * 64 * 4);
    unsigned* Z0b  = (unsigned*)p;  p += align256((size_t)n * 64 * 4);
    unsigned* Hb   = (unsigned*)p;  p += align256((size_t)n * 64 * 4);

    // ---- build padded CSC ----
    hipMemsetAsync(cur, 0, (size_t)n * 4, stream);
    hipMemsetAsync(eg, 0, (size_t)nnz_max * 4, stream);
    count_kernel<<<(e + 255) / 256, 256, 0, stream>>>(cols, cur, e);
    dinv_kernel<<<(n + 255) / 256, 256, 0, stream>>>(cur, dinv, n);
    scan_partial_kernel<<<nb, 256, 0, stream>>>(cur, bsum, n);
    scan_base_kernel<<<1, 64, 0, stream>>>(bsum, off, nb, n);
    scan_final_kernel<<<nb, 256, 0, stream>>>(cur, bsum, off, cur, n);
    fill_edges_kernel<<<(e + 255) / 256, 256, 0, stream>>>(rows, cols, dinv, cur, eg, e);
    fill_loops_kernel<<<(n + 255) / 256, 256, 0, stream>>>(dinv, cur, eg, n);

    // ---- weight transpose + input convert ----
    wtrans_kernel<<<32, 256, 0, stream>>>(W1, Wt);
    wtrans_kernel<<<32, 256, 0, stream>>>(W2, Wt + 8192);
    wtrans_kernel<<<32, 256, 0, stream>>>(W3, Wt + 16384);
    xconv_kernel<<<(n * 64 + 255) / 256, 256, 0, stream>>>(x, Hb, n * 64);

    const int gemm_grid = (n + 63) / 64;
    const int spmm_grid = (n + 7) / 8;
    const float* bl[3] = { b1, b2, b3 };

    for (int st = 0; st < 3; ++st) {
        gemm_mfma_kernel<<<gemm_grid, 256, 0, stream>>>(Hb, Wt + st * 8192, bl[st], Ab, Z0b, n);
        unsigned* bufs[2] = { Ab, Bb };
        int cu = 0;
        for (int k = 0; k < 10; ++k) {
            unsigned* o_ = (k == 9) ? Hb : bufs[cu ^ 1];
            spmm_bf16_kernel<<<spmm_grid, 256, 0, stream>>>(off, eg, bufs[cu], Z0b, o_, n, k == 9);
            cu ^= 1;
        }
    }

    head_kernel<<<(n + 15) / 16, 256, 0, stream>>>(Hb, Wc, bc, out, n);
}

// Round 8
// 1110.347 us; speedup vs baseline: 1.7491x; 1.0921x over previous
//
#include <hip/hip_runtime.h>
#include <math.h>

#define FD 128
#define NOUT 16
#define ALPHA_F 0.1f

typedef short short8 __attribute__((ext_vector_type(8)));
typedef float f32x4 __attribute__((ext_vector_type(4)));

// ---------- bf16 helpers (bit-level, RNE) ----------
__device__ __forceinline__ float bflo(unsigned u) { return __uint_as_float(u << 16); }
__device__ __forceinline__ float bfhi(unsigned u) { return __uint_as_float(u & 0xffff0000u); }
__device__ __forceinline__ unsigned f2bf(float f) {
    unsigned u = __float_as_uint(f);
    u += 0x7fffu + ((u >> 16) & 1u);          // round-to-nearest-even
    return u >> 16;
}
__device__ __forceinline__ unsigned pack2(float a, float b) {
    return f2bf(a) | (f2bf(b) << 16);
}

// ---------- CSC build ----------

__global__ void count_kernel(const int* __restrict__ cols, int* __restrict__ cnt, int e) {
    int i = blockIdx.x * blockDim.x + threadIdx.x;
    if (i < e) atomicAdd(&cnt[cols[i]], 1);
}

__global__ void dinv_kernel(const int* __restrict__ cnt, float* __restrict__ dinv, int n) {
    int i = blockIdx.x * blockDim.x + threadIdx.x;
    if (i < n) dinv[i] = rsqrtf((float)(cnt[i] + 1));   // +1 self-loop
}

// padded degree: true degree (cnt+1) rounded up to multiple of 8
__device__ __forceinline__ int padded(int cnt) { return (cnt + 8) & ~7; }

// three-kernel exclusive scan of padded degrees
__global__ void scan_partial_kernel(const int* __restrict__ cnt, int* __restrict__ bsum, int n) {
    __shared__ int sh[256];
    int base = blockIdx.x * 1024 + threadIdx.x * 4;
    int s = 0;
    #pragma unroll
    for (int j = 0; j < 4; ++j) { int i = base + j; if (i < n) s += padded(cnt[i]); }
    sh[threadIdx.x] = s; __syncthreads();
    for (int d = 128; d > 0; d >>= 1) {
        if ((int)threadIdx.x < d) sh[threadIdx.x] += sh[threadIdx.x + d];
        __syncthreads();
    }
    if (threadIdx.x == 0) bsum[blockIdx.x] = sh[0];
}

__global__ void scan_base_kernel(int* __restrict__ bsum, int* __restrict__ off, int nb, int n) {
    if (threadIdx.x == 0 && blockIdx.x == 0) {
        int run = 0;
        for (int b = 0; b < nb; ++b) { int t = bsum[b]; bsum[b] = run; run += t; }
        off[n] = run;
    }
}

// writes off[i] and cur[i]=off[i]. cnt and cur alias (read-before-write per thread).
__global__ void scan_final_kernel(const int* __restrict__ cnt, const int* __restrict__ bsum,
                                  int* __restrict__ off, int* __restrict__ cur, int n) {
    __shared__ int sh[256];
    int t = threadIdx.x;
    int base_i = blockIdx.x * 1024 + t * 4;
    int v[4]; int s = 0;
    #pragma unroll
    for (int j = 0; j < 4; ++j) { int i = base_i + j; v[j] = (i < n) ? padded(cnt[i]) : 0; s += v[j]; }
    sh[t] = s; __syncthreads();
    for (int d = 1; d < 256; d <<= 1) {
        int x = (t >= d) ? sh[t - d] : 0;
        __syncthreads();
        sh[t] += x;
        __syncthreads();
    }
    int excl = sh[t] - s + bsum[blockIdx.x];
    #pragma unroll
    for (int j = 0; j < 4; ++j) {
        int i = base_i + j;
        if (i < n) { off[i] = excl; cur[i] = excl; }
        excl += v[j];
    }
}

// edge record: low16 = src node id, high16 = bf16 weight
__global__ void fill_edges_kernel(const int* __restrict__ rows, const int* __restrict__ cols,
                                  const float* __restrict__ dinv, int* __restrict__ cur,
                                  unsigned* __restrict__ eg, int e) {
    int i = blockIdx.x * blockDim.x + threadIdx.x;
    if (i < e) {
        int r = rows[i];
        int c = cols[i];
        int pos = atomicAdd(&cur[c], 1);
        eg[pos] = (f2bf(dinv[r] * dinv[c]) << 16) | (unsigned)r;
    }
}

__global__ void fill_loops_kernel(const float* __restrict__ dinv, int* __restrict__ cur,
                                  unsigned* __restrict__ eg, int n) {
    int i = blockIdx.x * blockDim.x + threadIdx.x;
    if (i < n) {
        int pos = atomicAdd(&cur[i], 1);
        eg[pos] = (f2bf(dinv[i] * dinv[i]) << 16) | (unsigned)i;
    }
}

// ---------- pre-processing for MFMA GEMM ----------

// Wt[c][ku] = pack2(W[2ku][c], W[2ku+1][c]) : transposed, bf16-packed. 128x64 uints.
__global__ void wtrans_kernel(const float* __restrict__ W, unsigned* __restrict__ Wt) {
    int idx = blockIdx.x * 256 + threadIdx.x;
    if (idx < 128 * 64) {
        int c = idx >> 6, ku = idx & 63;
        Wt[idx] = pack2(W[(2 * ku) * FD + c], W[(2 * ku + 1) * FD + c]);
    }
}

// ---------- MFMA GEMM:  Y = X@W + b ; Ab = bf16(Y), Z0b = bf16(alpha*Y) ----------
// 256 thr = 4 waves; block covers 64 rows; wave w -> rows [blk*64+w*16, +16).
// K=128 in 4 steps of 32; N=128 as 8 tiles of 16. B^T (Wt) convention per m89/m92.
// BF_IN=0: A read directly from fp32 (stage 1, converted in-register, same RNE
// rounding as the packed path); BF_IN=1: A read from packed-bf16.
template <int BF_IN>
__global__ __launch_bounds__(256, 4)
void gemm_mfma_kernel(const void* __restrict__ Xv, const unsigned* __restrict__ Wt,
                      const float* __restrict__ bias,
                      unsigned* __restrict__ Ab, unsigned* __restrict__ Z0b, int n) {
    int l = threadIdx.x & 63;
    int w = threadIdx.x >> 6;
    int l15 = l & 15, lq = l >> 4;
    int r0 = blockIdx.x * 64 + w * 16;
    int arow = min(r0 + l15, n - 1);
    const unsigned* bptr = Wt + (size_t)l15 * 64 + lq * 4;

    f32x4 acc[8];
    #pragma unroll
    for (int nt = 0; nt < 8; ++nt) acc[nt] = (f32x4){0.f, 0.f, 0.f, 0.f};

    #pragma unroll
    for (int kk = 0; kk < 4; ++kk) {
        short8 af;
        if (BF_IN) {
            const unsigned* aptr = (const unsigned*)Xv + (size_t)arow * 64 + lq * 4;
            af = *(const short8*)(aptr + kk * 16);
        } else {
            const float* ap = (const float*)Xv + (size_t)arow * FD + lq * 8 + kk * 32;
            float4 fa = *(const float4*)(ap);
            float4 fb = *(const float4*)(ap + 4);
            unsigned p0 = pack2(fa.x, fa.y), p1 = pack2(fa.z, fa.w);
            unsigned p2 = pack2(fb.x, fb.y), p3 = pack2(fb.z, fb.w);
            uint4 u = make_uint4(p0, p1, p2, p3);
            af = *(const short8*)&u;
        }
        #pragma unroll
        for (int nt = 0; nt < 8; ++nt) {
            short8 bf = *(const short8*)(bptr + nt * 1024 + kk * 16);
            acc[nt] = __builtin_amdgcn_mfma_f32_16x16x32_bf16(af, bf, acc[nt], 0, 0, 0);
        }
    }

    #pragma unroll
    for (int nt = 0; nt < 8; ++nt) {
        float b_ = bias[nt * 16 + l15];
        #pragma unroll
        for (int j = 0; j < 4; ++j) {
            float v = acc[nt][j] + b_;
            float vp = __shfl_xor(v, 1);
            int row = r0 + lq * 4 + j;
            if (!(l & 1) && row < n) {
                int cu = nt * 8 + (l15 >> 1);
                Ab[(size_t)row * 64 + cu]  = pack2(v, vp);
                Z0b[(size_t)row * 64 + cu] = pack2(ALPHA_F * v, ALPHA_F * vp);
            }
        }
    }
}

// ---------- APPNP step: Xout = 0.9*A_hat@Xin + Z0b, fp32 accum ----------
// 2 nodes per wave (32 lanes each, uint2 = 4 bf16 features per lane).
// Padded degrees (mult of 8, zero-weight pads) -> aligned uint4 record loads.
// (R5 form: 8 gathers in flight, fits the 64-VGPR cap at 8 waves/SIMD.)
__global__ __launch_bounds__(256, 8)
void spmm_bf16_kernel(const int* __restrict__ off, const unsigned* __restrict__ eg,
                      const unsigned* __restrict__ Xin, const unsigned* __restrict__ X0b,
                      unsigned* __restrict__ Xout, int n, int relu) {
    int node = blockIdx.x * 8 + ((int)threadIdx.x >> 5);
    if (node >= n) return;
    int lane31 = threadIdx.x & 31;
    int s = off[node];
    int degpad = off[node + 1] - s;               // multiple of 8, >= 8
    int dother = __shfl_xor(degpad, 32);          // other half's degpad
    int dm = max(degpad, dother);
    const uint2* Xg = (const uint2*)Xin;
    uint2 x0 = ((const uint2*)X0b)[node * 32 + lane31];   // issue early
    float a0 = 0.f, a1 = 0.f, a2 = 0.f, a3 = 0.f;

    for (int base = 0; base < dm; base += 8) {
        int p = s + min(base, degpad - 8);
        bool live = base < degpad;                // beyond-own-end chunks masked
        uint4 ra = *(const uint4*)(eg + p);
        uint4 rb = *(const uint4*)(eg + p + 4);
        uint2 g0 = Xg[(ra.x & 0xffffu) * 32 + lane31];
        uint2 g1 = Xg[(ra.y & 0xffffu) * 32 + lane31];
        uint2 g2 = Xg[(ra.z & 0xffffu) * 32 + lane31];
        uint2 g3 = Xg[(ra.w & 0xffffu) * 32 + lane31];
        uint2 g4 = Xg[(rb.x & 0xffffu) * 32 + lane31];
        uint2 g5 = Xg[(rb.y & 0xffffu) * 32 + lane31];
        uint2 g6 = Xg[(rb.z & 0xffffu) * 32 + lane31];
        uint2 g7 = Xg[(rb.w & 0xffffu) * 32 + lane31];
        float w0 = live ? bfhi(ra.x) : 0.f;
        float w1 = live ? bfhi(ra.y) : 0.f;
        float w2 = live ? bfhi(ra.z) : 0.f;
        float w3 = live ? bfhi(ra.w) : 0.f;
        float w4 = live ? bfhi(rb.x) : 0.f;
        float w5 = live ? bfhi(rb.y) : 0.f;
        float w6 = live ? bfhi(rb.z) : 0.f;
        float w7 = live ? bfhi(rb.w) : 0.f;
        a0 += w0 * bflo(g0.x); a1 += w0 * bfhi(g0.x); a2 += w0 * bflo(g0.y); a3 += w0 * bfhi(g0.y);
        a0 += w1 * bflo(g1.x); a1 += w1 * bfhi(g1.x); a2 += w1 * bflo(g1.y); a3 += w1 * bfhi(g1.y);
        a0 += w2 * bflo(g2.x); a1 += w2 * bfhi(g2.x); a2 += w2 * bflo(g2.y); a3 += w2 * bfhi(g2.y);
        a0 += w3 * bflo(g3.x); a1 += w3 * bfhi(g3.x); a2 += w3 * bflo(g3.y); a3 += w3 * bfhi(g3.y);
        a0 += w4 * bflo(g4.x); a1 += w4 * bfhi(g4.x); a2 += w4 * bflo(g4.y); a3 += w4 * bfhi(g4.y);
        a0 += w5 * bflo(g5.x); a1 += w5 * bfhi(g5.x); a2 += w5 * bflo(g5.y); a3 += w5 * bfhi(g5.y);
        a0 += w6 * bflo(g6.x); a1 += w6 * bfhi(g6.x); a2 += w6 * bflo(g6.y); a3 += w6 * bfhi(g6.y);
        a0 += w7 * bflo(g7.x); a1 += w7 * bfhi(g7.x); a2 += w7 * bflo(g7.y); a3 += w7 * bfhi(g7.y);
    }

    float v0 = 0.9f * a0 + bflo(x0.x);
    float v1 = 0.9f * a1 + bfhi(x0.x);
    float v2 = 0.9f * a2 + bflo(x0.y);
    float v3 = 0.9f * a3 + bfhi(x0.y);
    if (relu) {
        v0 = fmaxf(v0, 0.f); v1 = fmaxf(v1, 0.f);
        v2 = fmaxf(v2, 0.f); v3 = fmaxf(v3, 0.f);
    }
    ((uint2*)Xout)[node * 32 + lane31] = make_uint2(pack2(v0, v1), pack2(v2, v3));
}

// ---------- head: logits = H @ Wc + bc ; log_softmax. 16 lanes/node ----------
__global__ void head_kernel(const unsigned* __restrict__ Hb, const float* __restrict__ Wc,
                            const float* __restrict__ bc, float* __restrict__ out, int n) {
    int t = threadIdx.x;
    int o = t & (NOUT - 1);
    int node = blockIdx.x * (256 / NOUT) + (t >> 4);
    if (node >= n) return;
    float acc = bc[o];
    const uint4* hrow = (const uint4*)(Hb + (size_t)node * 64);
    #pragma unroll 4
    for (int k4 = 0; k4 < 16; ++k4) {
        uint4 u = hrow[k4];
        int k = k4 * 8;
        acc += bflo(u.x) * Wc[(k + 0) * NOUT + o];
        acc += bfhi(u.x) * Wc[(k + 1) * NOUT + o];
        acc += bflo(u.y) * Wc[(k + 2) * NOUT + o];
        acc += bfhi(u.y) * Wc[(k + 3) * NOUT + o];
        acc += bflo(u.z) * Wc[(k + 4) * NOUT + o];
        acc += bfhi(u.z) * Wc[(k + 5) * NOUT + o];
        acc += bflo(u.w) * Wc[(k + 6) * NOUT + o];
        acc += bfhi(u.w) * Wc[(k + 7) * NOUT + o];
    }
    float m = acc;
    #pragma unroll
    for (int d = NOUT / 2; d > 0; d >>= 1) m = fmaxf(m, __shfl_xor(m, d, NOUT));
    float ex = __expf(acc - m);
    float s = ex;
    #pragma unroll
    for (int d = NOUT / 2; d > 0; d >>= 1) s += __shfl_xor(s, d, NOUT);
    out[node * NOUT + o] = acc - m - __logf(s);
}

// ---------- launch ----------

static inline size_t align256(size_t x) { return (x + 255) & ~(size_t)255; }

extern "C" void kernel_launch(void* const* d_in, const int* in_sizes, int n_in,
                              void* d_out, int out_size, void* d_ws, size_t ws_size,
                              hipStream_t stream) {
    const float* x  = (const float*)d_in[0];
    const int*   ei = (const int*)d_in[1];
    const float* W1 = (const float*)d_in[2];
    const float* b1 = (const float*)d_in[3];
    const float* W2 = (const float*)d_in[4];
    const float* b2 = (const float*)d_in[5];
    const float* W3 = (const float*)d_in[6];
    const float* b3 = (const float*)d_in[7];
    const float* Wc = (const float*)d_in[8];
    const float* bc = (const float*)d_in[9];
    float* out = (float*)d_out;

    const int n = in_sizes[0] / FD;       // 50000
    const int e = in_sizes[1] / 2;        // 800000
    const int nnz_max = e + n + 8 * n + 16;   // padded upper bound
    const int nb = (n + 1023) / 1024;

    const int* rows = ei;
    const int* cols = ei + e;

    // workspace layout (~57 MB)
    char* p = (char*)d_ws;
    int*      off  = (int*)p;       p += align256((size_t)(n + 1) * 4);
    int*      cur  = (int*)p;       p += align256((size_t)n * 4);
    float*    dinv = (float*)p;     p += align256((size_t)n * 4);
    int*      bsum = (int*)p;       p += align256((size_t)nb * 4);
    unsigned* eg   = (unsigned*)p;  p += align256((size_t)nnz_max * 4);
    unsigned* Wt   = (unsigned*)p;  p += align256((size_t)3 * 8192 * 4);
    unsigned* Ab   = (unsigned*)p;  p += align256((size_t)n * 64 * 4);
    unsigned* Bb   = (unsigned*)p;  p += align256((size_t)n * 64 * 4);
    unsigned* Z0b  = (unsigned*)p;  p += align256((size_t)n * 64 * 4);
    unsigned* Hb   = (unsigned*)p;  p += align256((size_t)n * 64 * 4);

    // ---- build padded CSC ----
    hipMemsetAsync(cur, 0, (size_t)n * 4, stream);
    hipMemsetAsync(eg, 0, (size_t)nnz_max * 4, stream);
    count_kernel<<<(e + 255) / 256, 256, 0, stream>>>(cols, cur, e);
    dinv_kernel<<<(n + 255) / 256, 256, 0, stream>>>(cur, dinv, n);
    scan_partial_kernel<<<nb, 256, 0, stream>>>(cur, bsum, n);
    scan_base_kernel<<<1, 64, 0, stream>>>(bsum, off, nb, n);
    scan_final_kernel<<<nb, 256, 0, stream>>>(cur, bsum, off, cur, n);
    fill_edges_kernel<<<(e + 255) / 256, 256, 0, stream>>>(rows, cols, dinv, cur, eg, e);
    fill_loops_kernel<<<(n + 255) / 256, 256, 0, stream>>>(dinv, cur, eg, n);

    // ---- weight transpose ----
    wtrans_kernel<<<32, 256, 0, stream>>>(W1, Wt);
    wtrans_kernel<<<32, 256, 0, stream>>>(W2, Wt + 8192);
    wtrans_kernel<<<32, 256, 0, stream>>>(W3, Wt + 16384);

    const int gemm_grid = (n + 63) / 64;
    const int spmm_grid = (n + 7) / 8;
    const float* bl[3] = { b1, b2, b3 };
    const void* gin = x;

    for (int st = 0; st < 3; ++st) {
        if (st == 0)
            gemm_mfma_kernel<0><<<gemm_grid, 256, 0, stream>>>(gin, Wt, bl[st], Ab, Z0b, n);
        else
            gemm_mfma_kernel<1><<<gemm_grid, 256, 0, stream>>>(gin, Wt + st * 8192, bl[st], Ab, Z0b, n);
        unsigned* bufs[2] = { Ab, Bb };
        int cu = 0;
        for (int k = 0; k < 10; ++k) {
            unsigned* o_ = (k == 9) ? Hb : bufs[cu ^ 1];
            spmm_bf16_kernel<<<spmm_grid, 256, 0, stream>>>(off, eg, bufs[cu], Z0b, o_, n, k == 9);
            cu ^= 1;
        }
        gin = Hb;
    }

    head_kernel<<<(n + 15) / 16, 256, 0, stream>>>(Hb, Wc, bc, out, n);
}